// Round 2
// baseline (139.180 us; speedup 1.0000x reference)
//
#include <hip/hip_runtime.h>
#include <hip/hip_bf16.h>

#define ALPHA 0.2f
#define NROW 8192

typedef __attribute__((ext_vector_type(4))) float f4;
typedef __attribute__((ext_vector_type(8))) short s8;

__device__ __forceinline__ short f2bf_bits(float x){
    __hip_bfloat16 b = __float2bfloat16(x);
    return __builtin_bit_cast(short, b);
}

// K1: h = x@W ; s1 = h@a1 ; s2 = h@a2 ; hT[f][i] = bf16(h[i][f])
__global__ __launch_bounds__(256) void k_proj(
    const float* __restrict__ x, const float* __restrict__ W, const float* __restrict__ a,
    float* __restrict__ s1, float* __restrict__ s2, __hip_bfloat16* __restrict__ hT)
{
    __shared__ float Wsh[128*64];
    __shared__ float xsh[4*128];
    const int t = threadIdx.x;
    const int f = t & 63, ry = t >> 6;
    const int row0 = blockIdx.x * 4;
    for (int i = t; i < 128*64; i += 256) Wsh[i] = W[i];
    for (int i = t; i < 4*128; i += 256) xsh[i] = x[row0*128 + i];
    __syncthreads();
    float acc = 0.f;
    #pragma unroll
    for (int k = 0; k < 128; ++k) acc = fmaf(xsh[ry*128 + k], Wsh[k*64 + f], acc);
    float p1 = acc * a[f], p2 = acc * a[64 + f];
    #pragma unroll
    for (int m = 32; m; m >>= 1){ p1 += __shfl_xor(p1, m, 64); p2 += __shfl_xor(p2, m, 64); }
    const int row = row0 + ry;
    if (f == 0){ s1[row] = p1; s2[row] = p2; }
    hT[f * NROW + row] = __float2bfloat16(acc);
}

// K2: s2max = max(s2)
__global__ __launch_bounds__(256) void k_s2max(const float* __restrict__ s2, float* __restrict__ s2max)
{
    __shared__ float red[256];
    float m = -1e30f;
    for (int i = threadIdx.x; i < NROW; i += 256) m = fmaxf(m, s2[i]);
    red[threadIdx.x] = m; __syncthreads();
    for (int s = 128; s; s >>= 1){
        if (threadIdx.x < (unsigned)s) red[threadIdx.x] = fmaxf(red[threadIdx.x], red[threadIdx.x + s]);
        __syncthreads();
    }
    if (threadIdx.x == 0) s2max[0] = red[0];
}

// K-mask: pure streaming compress adj -> 1 bit per entry.
// word w covers adj[w*32 .. w*32+32); bit b = adj[w*32+b] > 0
__global__ __launch_bounds__(256) void k_mask(
    const float* __restrict__ adj, unsigned* __restrict__ mask32)
{
    const long w = (long)blockIdx.x * 256 + threadIdx.x;
    const float* p = adj + w * 32;
    f4 v[8];
    #pragma unroll
    for (int i = 0; i < 8; ++i) v[i] = *(const f4*)(p + i*4);
    unsigned m = 0;
    #pragma unroll
    for (int i = 0; i < 8; ++i){
        #pragma unroll
        for (int e = 0; e < 4; ++e)
            m |= (v[i][e] > 0.f) ? (1u << (i*4 + e)) : 0u;
    }
    mask32[w] = m;
}

// K3 (new): masked softmax from bitmask (L3-hot) + PV via bf16 MFMA + ELU.
__global__ __launch_bounds__(512, 4) void k_attn2(
    const unsigned* __restrict__ mask32, const float* __restrict__ s1g,
    const float* __restrict__ s2g, const float* __restrict__ s2maxp,
    const __hip_bfloat16* __restrict__ hT, float* __restrict__ out)
{
    const int N = NROW;
    const int tid  = threadIdx.x;
    const int wave = tid >> 6, lane = tid & 63;
    const int lr = lane & 15;     // A-row / C-col
    const int hi = lane >> 4;     // k-group 0..3
    const int hi8 = hi * 8;
    const int i0 = blockIdx.x * 16;
    const int row = i0 + lr;

    const float s1r = s1g[row];
    float Mr = s1r + s2maxp[0];
    Mr = fmaxf(Mr, ALPHA * Mr);   // lrelu(s1r + s2max) >= true row max

    const int jseg = wave * 1024;
    const unsigned* maskp = mask32 + row * 256 + wave * 32;   // 32 words = 1024 cols
    const float* s2p = s2g + jseg + hi8;
    const __hip_bfloat16* hp = hT + lr * N + jseg + hi8;

    f4 acc0 = {0.f,0.f,0.f,0.f}, acc1 = {0.f,0.f,0.f,0.f};
    f4 acc2 = {0.f,0.f,0.f,0.f}, acc3 = {0.f,0.f,0.f,0.f};
    float lsum = 0.f;

    unsigned mw0, mw1;
    f4 s2A0, s2B0; s8 h00, h10, h20, h30;
    f4 s2A1, s2B1; s8 h01, h11, h21, h31;

#define LOADB(B, c) do { \
    mw##B = maskp[(c)]; \
    const float* sp = s2p + (c)*32; \
    s2A##B = *(const f4*)(sp);       s2B##B = *(const f4*)(sp + 4); \
    const __hip_bfloat16* hq = hp + (c)*32; \
    h0##B = *(const s8*)(hq); \
    h1##B = *(const s8*)(hq + 16*NROW); \
    h2##B = *(const s8*)(hq + 32*NROW); \
    h3##B = *(const s8*)(hq + 48*NROW); \
} while(0)

#define CALC(sv, bc, q) { float tv = s1r + (sv); tv = fmaxf(tv, ALPHA*tv); \
    float pe = __expf(tv - Mr); q = (mb & (bc)) ? pe : 0.f; }

#define COMPB(B) do { \
    unsigned mb = mw##B >> hi8; \
    float q0,q1,q2,q3,q4,q5,q6,q7; \
    CALC(s2A##B[0], 1u, q0); CALC(s2A##B[1], 2u, q1); \
    CALC(s2A##B[2], 4u, q2); CALC(s2A##B[3], 8u, q3); \
    CALC(s2B##B[0], 16u, q4); CALC(s2B##B[1], 32u, q5); \
    CALC(s2B##B[2], 64u, q6); CALC(s2B##B[3], 128u, q7); \
    lsum += ((q0+q1)+(q2+q3)) + ((q4+q5)+(q6+q7)); \
    s8 af; \
    af[0]=f2bf_bits(q0); af[1]=f2bf_bits(q1); af[2]=f2bf_bits(q2); af[3]=f2bf_bits(q3); \
    af[4]=f2bf_bits(q4); af[5]=f2bf_bits(q5); af[6]=f2bf_bits(q6); af[7]=f2bf_bits(q7); \
    acc0 = __builtin_amdgcn_mfma_f32_16x16x32_bf16(af, h0##B, acc0, 0, 0, 0); \
    acc1 = __builtin_amdgcn_mfma_f32_16x16x32_bf16(af, h1##B, acc1, 0, 0, 0); \
    acc2 = __builtin_amdgcn_mfma_f32_16x16x32_bf16(af, h2##B, acc2, 0, 0, 0); \
    acc3 = __builtin_amdgcn_mfma_f32_16x16x32_bf16(af, h3##B, acc3, 0, 0, 0); \
} while(0)

    LOADB(0, 0);
    for (int c = 0; c < 30; c += 2){
        LOADB(1, c+1);
        COMPB(0);
        LOADB(0, c+2);
        COMPB(1);
    }
    LOADB(1, 31);
    COMPB(0);
    COMPB(1);

#undef LOADB
#undef CALC
#undef COMPB

    lsum += __shfl_xor(lsum, 16, 64);
    lsum += __shfl_xor(lsum, 32, 64);

    __shared__ float accb[8][16][64];   // 32 KB
    __shared__ float lsb[8][16];

    // C layout: col = lane&15, row = (lane>>4)*4 + reg
    #pragma unroll
    for (int r = 0; r < 4; ++r){
        accb[wave][hi*4 + r][ 0 + lr] = acc0[r];
        accb[wave][hi*4 + r][16 + lr] = acc1[r];
        accb[wave][hi*4 + r][32 + lr] = acc2[r];
        accb[wave][hi*4 + r][48 + lr] = acc3[r];
    }
    if (lane < 16) lsb[wave][lane] = lsum;
    __syncthreads();

    for (int idx = tid; idx < 16*64; idx += 512){
        int r = idx >> 6, cf = idx & 63;
        float s = 0.f, L = 0.f;
        #pragma unroll
        for (int w = 0; w < 8; ++w){ s += accb[w][r][cf]; L += lsb[w][r]; }
        float v = s / L;
        out[(long)(i0 + r)*64 + cf] = (v > 0.f) ? v : expm1f(v);
    }
}

// Fallback (round-1 proven path) if ws is too small for the mask.
__global__ __launch_bounds__(512, 4) void k_attn_fb(
    const float* __restrict__ adj, const float* __restrict__ s1g,
    const float* __restrict__ s2g, const float* __restrict__ s2maxp,
    const __hip_bfloat16* __restrict__ hT, float* __restrict__ out)
{
    const int N = NROW;
    const int tid  = threadIdx.x;
    const int wave = tid >> 6, lane = tid & 63;
    const int lr = lane & 15;
    const int hi = lane >> 4;
    const int i0 = blockIdx.x * 16;
    const int row = i0 + lr;

    const float s1r = s1g[row];
    float Mr = s1r + s2maxp[0];
    Mr = fmaxf(Mr, ALPHA * Mr);

    const int jseg = wave * 1024;
    const float* adjp = adj + (long)row * N + jseg + hi*8;
    const float* s2p  = s2g + jseg + hi*8;
    const __hip_bfloat16* hp = hT + lr * N + jseg + hi*8;

    f4 acc0 = {0.f,0.f,0.f,0.f}, acc1 = {0.f,0.f,0.f,0.f};
    f4 acc2 = {0.f,0.f,0.f,0.f}, acc3 = {0.f,0.f,0.f,0.f};
    float lsum = 0.f;

    f4 adjA0, adjB0, s2A0, s2B0; s8 h00, h10, h20, h30;
    f4 adjA1, adjB1, s2A1, s2B1; s8 h01, h11, h21, h31;

#define LOADB(B, c) do { \
    const float* ap = adjp + (c)*32; \
    adjA##B = *(const f4*)(ap);      adjB##B = *(const f4*)(ap + 4); \
    const float* sp = s2p + (c)*32; \
    s2A##B = *(const f4*)(sp);       s2B##B = *(const f4*)(sp + 4); \
    const __hip_bfloat16* hq = hp + (c)*32; \
    h0##B = *(const s8*)(hq); \
    h1##B = *(const s8*)(hq + 16*NROW); \
    h2##B = *(const s8*)(hq + 32*NROW); \
    h3##B = *(const s8*)(hq + 48*NROW); \
} while(0)

#define CALC(sv, av, q) { float tv = s1r + (sv); tv = fmaxf(tv, ALPHA*tv); \
    float pe = __expf(tv - Mr); q = ((av) > 0.f) ? pe : 0.f; }

#define COMPB(B) do { \
    float q0,q1,q2,q3,q4,q5,q6,q7; \
    CALC(s2A##B[0], adjA##B[0], q0); CALC(s2A##B[1], adjA##B[1], q1); \
    CALC(s2A##B[2], adjA##B[2], q2); CALC(s2A##B[3], adjA##B[3], q3); \
    CALC(s2B##B[0], adjB##B[0], q4); CALC(s2B##B[1], adjB##B[1], q5); \
    CALC(s2B##B[2], adjB##B[2], q6); CALC(s2B##B[3], adjB##B[3], q7); \
    lsum += ((q0+q1)+(q2+q3)) + ((q4+q5)+(q6+q7)); \
    s8 af; \
    af[0]=f2bf_bits(q0); af[1]=f2bf_bits(q1); af[2]=f2bf_bits(q2); af[3]=f2bf_bits(q3); \
    af[4]=f2bf_bits(q4); af[5]=f2bf_bits(q5); af[6]=f2bf_bits(q6); af[7]=f2bf_bits(q7); \
    acc0 = __builtin_amdgcn_mfma_f32_16x16x32_bf16(af, h0##B, acc0, 0, 0, 0); \
    acc1 = __builtin_amdgcn_mfma_f32_16x16x32_bf16(af, h1##B, acc1, 0, 0, 0); \
    acc2 = __builtin_amdgcn_mfma_f32_16x16x32_bf16(af, h2##B, acc2, 0, 0, 0); \
    acc3 = __builtin_amdgcn_mfma_f32_16x16x32_bf16(af, h3##B, acc3, 0, 0, 0); \
} while(0)

    LOADB(0, 0);
    for (int c = 0; c < 30; c += 2){
        LOADB(1, c+1);
        COMPB(0);
        LOADB(0, c+2);
        COMPB(1);
    }
    LOADB(1, 31);
    COMPB(0);
    COMPB(1);

#undef LOADB
#undef CALC
#undef COMPB

    lsum += __shfl_xor(lsum, 16, 64);
    lsum += __shfl_xor(lsum, 32, 64);

    __shared__ float accb[8][16][64];
    __shared__ float lsb[8][16];

    #pragma unroll
    for (int r = 0; r < 4; ++r){
        accb[wave][hi*4 + r][ 0 + lr] = acc0[r];
        accb[wave][hi*4 + r][16 + lr] = acc1[r];
        accb[wave][hi*4 + r][32 + lr] = acc2[r];
        accb[wave][hi*4 + r][48 + lr] = acc3[r];
    }
    if (lane < 16) lsb[wave][lane] = lsum;
    __syncthreads();

    for (int idx = tid; idx < 16*64; idx += 512){
        int r = idx >> 6, cf = idx & 63;
        float s = 0.f, L = 0.f;
        #pragma unroll
        for (int w = 0; w < 8; ++w){ s += accb[w][r][cf]; L += lsb[w][r]; }
        float v = s / L;
        out[(long)(i0 + r)*64 + cf] = (v > 0.f) ? v : expm1f(v);
    }
}

extern "C" void kernel_launch(void* const* d_in, const int* in_sizes, int n_in,
                              void* d_out, int out_size, void* d_ws, size_t ws_size,
                              hipStream_t stream)
{
    const float* x   = (const float*)d_in[0];
    const float* adj = (const float*)d_in[1];
    const float* W   = (const float*)d_in[2];
    const float* a   = (const float*)d_in[3];
    float* out = (float*)d_out;

    char* ws = (char*)d_ws;
    float* s1    = (float*)(ws);                       // 32 KB
    float* s2    = (float*)(ws + 32768);               // 32 KB
    float* s2mx  = (float*)(ws + 65536);               // 256 B
    __hip_bfloat16* hT = (__hip_bfloat16*)(ws + 65792);        // 1 MB
    unsigned* mask32 = (unsigned*)(ws + 65792 + 1048576);      // 8 MB
    const size_t NEED = 65792 + 1048576 + 8388608;

    k_proj <<<2048, 256, 0, stream>>>(x, W, a, s1, s2, hT);
    k_s2max<<<   1, 256, 0, stream>>>(s2, s2mx);
    if (ws_size >= NEED){
        k_mask <<<8192, 256, 0, stream>>>(adj, mask32);
        k_attn2<<< 512, 512, 0, stream>>>(mask32, s1, s2, s2mx, hT, out);
    } else {
        k_attn_fb<<<512, 512, 0, stream>>>(adj, s1, s2, s2mx, hT, out);
    }
}

// Round 3
// 104.543 us; speedup vs baseline: 1.3313x; 1.3313x over previous
//
#include <hip/hip_runtime.h>
#include <hip/hip_bf16.h>

#define ALPHA 0.2f
#define NROW 8192
#define JB 256
#define NSTEP (NROW/JB)

typedef __attribute__((ext_vector_type(4))) float f4;
typedef __attribute__((ext_vector_type(8))) short s8;

__device__ __forceinline__ short f2bf_bits(float x){
    __hip_bfloat16 b = __float2bfloat16(x);
    return __builtin_bit_cast(short, b);
}

__device__ __forceinline__ void gload_lds16(const void* g, void* l){
    __builtin_amdgcn_global_load_lds(
        (const __attribute__((address_space(1))) void*)g,
        (__attribute__((address_space(3))) void*)l, 16, 0, 0);
}

// K1: h = x@W ; s1 ; s2 ; F1=exp(s2) ; F2=exp(0.2*s2) ; hT[f][i] = bf16(h[i][f])
__global__ __launch_bounds__(256) void k_proj(
    const float* __restrict__ x, const float* __restrict__ W, const float* __restrict__ a,
    float* __restrict__ s1, float* __restrict__ s2,
    float* __restrict__ F1, float* __restrict__ F2, __hip_bfloat16* __restrict__ hT)
{
    __shared__ float Wsh[128*64];
    __shared__ float xsh[4*128];
    const int t = threadIdx.x;
    const int f = t & 63, ry = t >> 6;
    const int row0 = blockIdx.x * 4;
    for (int i = t; i < 128*64; i += 256) Wsh[i] = W[i];
    for (int i = t; i < 4*128; i += 256) xsh[i] = x[row0*128 + i];
    __syncthreads();
    float acc = 0.f;
    #pragma unroll
    for (int k = 0; k < 128; ++k) acc = fmaf(xsh[ry*128 + k], Wsh[k*64 + f], acc);
    float p1 = acc * a[f], p2 = acc * a[64 + f];
    #pragma unroll
    for (int m = 32; m; m >>= 1){ p1 += __shfl_xor(p1, m, 64); p2 += __shfl_xor(p2, m, 64); }
    const int row = row0 + ry;
    if (f == 0){
        s1[row] = p1; s2[row] = p2;
        F1[row] = __expf(p2); F2[row] = __expf(0.2f * p2);
    }
    hT[f * NROW + row] = __float2bfloat16(acc);
}

// K2: s2max = max(s2)
__global__ __launch_bounds__(256) void k_s2max(const float* __restrict__ s2, float* __restrict__ s2max)
{
    __shared__ float red[256];
    float m = -1e30f;
    for (int i = threadIdx.x; i < NROW; i += 256) m = fmaxf(m, s2[i]);
    red[threadIdx.x] = m; __syncthreads();
    for (int s = 128; s; s >>= 1){
        if (threadIdx.x < (unsigned)s) red[threadIdx.x] = fmaxf(red[threadIdx.x], red[threadIdx.x + s]);
        __syncthreads();
    }
    if (threadIdx.x == 0) s2max[0] = red[0];
}

// K3: adj streamed HBM->LDS via global_load_lds (double-buffered, source-swizzled),
// factored softmax (no exp in inner loop), PV via bf16 MFMA, ELU epilogue.
__global__ __launch_bounds__(512, 4) void k_attn3(
    const float* __restrict__ adj, const float* __restrict__ s1g,
    const float* __restrict__ s2maxp, const float* __restrict__ F1g,
    const float* __restrict__ F2g, const __hip_bfloat16* __restrict__ hT,
    float* __restrict__ out)
{
    __shared__ float adjT[2][16][JB];   // 32 KB, physical unit u of row c holds logical unit u^(c&7)
    __shared__ float Fb[2][2][JB];      // 4 KB
    __shared__ float accb[8][16][64];   // 32 KB
    __shared__ float lsb[8][16];

    const int tid  = threadIdx.x;
    const int w    = tid >> 6, lane = tid & 63;
    const int lr   = lane & 15;     // A-row / C-col
    const int hi   = lane >> 4;     // k-group 0..3
    const int i0   = blockIdx.x * 16;
    const int row  = i0 + lr;

    const float s1r = s1g[row];
    const float t0  = s1r + s2maxp[0];
    const float Mr  = fmaxf(t0, ALPHA * t0);      // >= true row max of lrelu logits
    const float E1  = __expf(s1r - Mr);           // t>0 branch:  p = E1*F1_j
    const float E2  = __expf(ALPHA * s1r - Mr);   // t<=0 branch: p = E2*F2_j
    const float T1  = __expf(-s1r);               // cond (t>0) <=> F1_j > T1

#define STAGE(b, js) do { \
    const int j0s = (js) * JB; \
    _Pragma("unroll") \
    for (int q = 0; q < 2; ++q){ \
        const int c = w*2 + q; \
        gload_lds16(adj + (long)(i0 + c)*NROW + j0s + ((lane ^ (c & 7)) << 2), \
                    &adjT[b][c][0]); \
    } \
    if (w == 0) gload_lds16(F1g + j0s + (lane << 2), &Fb[b][0][0]); \
    if (w == 1) gload_lds16(F2g + j0s + (lane << 2), &Fb[b][1][0]); \
} while(0)

    STAGE(0, 0);

    f4 acc0 = {0.f,0.f,0.f,0.f}, acc1 = {0.f,0.f,0.f,0.f};
    f4 acc2 = {0.f,0.f,0.f,0.f}, acc3 = {0.f,0.f,0.f,0.f};
    float lsum = 0.f;

    const int vbase = w*8 + hi*2;   // logical 16B-unit within row
    const int sw    = lr & 7;

    __syncthreads();   // drains prologue staging (vmcnt(0) + barrier)

    for (int t = 0; t < NSTEP; ++t){
        const int b = t & 1;
        if (t + 1 < NSTEP) STAGE(b ^ 1, t + 1);

        const int j0 = t * JB;
        // hT B-fragments (L2-resident): issue early
        const __hip_bfloat16* hq = hT + lr*NROW + j0 + w*32 + hi*8;
        s8 h0 = *(const s8*)(hq);
        s8 h1 = *(const s8*)(hq + 16*NROW);
        s8 h2 = *(const s8*)(hq + 32*NROW);
        s8 h3 = *(const s8*)(hq + 48*NROW);

        // adj fragment: logical units vbase, vbase+1 -> swizzled slots
        f4 a0 = *(const f4*)&adjT[b][lr][(( vbase      ^ sw) << 2)];
        f4 a1 = *(const f4*)&adjT[b][lr][(((vbase + 1) ^ sw) << 2)];
        // F fragments (broadcast within 16-lane groups)
        const int fo = w*32 + hi*8;
        f4 f1a = *(const f4*)&Fb[b][0][fo],   f1b = *(const f4*)&Fb[b][0][fo + 4];
        f4 f2a = *(const f4*)&Fb[b][1][fo],   f2b = *(const f4*)&Fb[b][1][fo + 4];

        float q0,q1,q2,q3,q4,q5,q6,q7;
#define CALC(av, g1, g2, qd) { \
        float fz = ((g1) > T1) ? (g1)*E1 : (g2)*E2; \
        qd = ((av) > 0.f) ? fz : 0.f; }
        CALC(a0[0], f1a[0], f2a[0], q0); CALC(a0[1], f1a[1], f2a[1], q1);
        CALC(a0[2], f1a[2], f2a[2], q2); CALC(a0[3], f1a[3], f2a[3], q3);
        CALC(a1[0], f1b[0], f2b[0], q4); CALC(a1[1], f1b[1], f2b[1], q5);
        CALC(a1[2], f1b[2], f2b[2], q6); CALC(a1[3], f1b[3], f2b[3], q7);
#undef CALC
        lsum += ((q0+q1)+(q2+q3)) + ((q4+q5)+(q6+q7));

        s8 af;
        af[0]=f2bf_bits(q0); af[1]=f2bf_bits(q1); af[2]=f2bf_bits(q2); af[3]=f2bf_bits(q3);
        af[4]=f2bf_bits(q4); af[5]=f2bf_bits(q5); af[6]=f2bf_bits(q6); af[7]=f2bf_bits(q7);
        acc0 = __builtin_amdgcn_mfma_f32_16x16x32_bf16(af, h0, acc0, 0, 0, 0);
        acc1 = __builtin_amdgcn_mfma_f32_16x16x32_bf16(af, h1, acc1, 0, 0, 0);
        acc2 = __builtin_amdgcn_mfma_f32_16x16x32_bf16(af, h2, acc2, 0, 0, 0);
        acc3 = __builtin_amdgcn_mfma_f32_16x16x32_bf16(af, h3, acc3, 0, 0, 0);

        __syncthreads();   // staging of b^1 complete; all reads of b done
    }
#undef STAGE

    lsum += __shfl_xor(lsum, 16, 64);
    lsum += __shfl_xor(lsum, 32, 64);

    // C layout: col = lane&15, row = (lane>>4)*4 + reg
    #pragma unroll
    for (int r = 0; r < 4; ++r){
        accb[w][hi*4 + r][ 0 + lr] = acc0[r];
        accb[w][hi*4 + r][16 + lr] = acc1[r];
        accb[w][hi*4 + r][32 + lr] = acc2[r];
        accb[w][hi*4 + r][48 + lr] = acc3[r];
    }
    if (lane < 16) lsb[w][lane] = lsum;
    __syncthreads();

    for (int idx = tid; idx < 16*64; idx += 512){
        int r = idx >> 6, cf = idx & 63;
        float s = 0.f, L = 0.f;
        #pragma unroll
        for (int ww = 0; ww < 8; ++ww){ s += accb[ww][r][cf]; L += lsb[ww][r]; }
        float v = s / L;
        out[(long)(i0 + r)*64 + cf] = (v > 0.f) ? v : expm1f(v);
    }
}

extern "C" void kernel_launch(void* const* d_in, const int* in_sizes, int n_in,
                              void* d_out, int out_size, void* d_ws, size_t ws_size,
                              hipStream_t stream)
{
    const float* x   = (const float*)d_in[0];
    const float* adj = (const float*)d_in[1];
    const float* W   = (const float*)d_in[2];
    const float* a   = (const float*)d_in[3];
    float* out = (float*)d_out;

    char* ws = (char*)d_ws;
    float* s1   = (float*)(ws);                    // 32 KB
    float* s2   = (float*)(ws + 32768);            // 32 KB
    float* F1   = (float*)(ws + 65536);            // 32 KB
    float* F2   = (float*)(ws + 98304);            // 32 KB
    float* s2mx = (float*)(ws + 131072);           // 256 B
    __hip_bfloat16* hT = (__hip_bfloat16*)(ws + 131328);   // 1 MB

    k_proj <<<2048, 256, 0, stream>>>(x, W, a, s1, s2, F1, F2, hT);
    k_s2max<<<   1, 256, 0, stream>>>(s2, s2mx);
    k_attn3<<< 512, 512, 0, stream>>>(adj, s1, s2mx, F1, F2, hT, out);
}